// Round 1
// baseline (933.706 us; speedup 1.0000x reference)
//
#include <hip/hip_runtime.h>
#include <hip/hip_bf16.h>

// Transformer block: x:[8,2048,768] fp32. All GEMMs in bf16 MFMA (fp32 acc).
// Workspace layout (bytes):
//   [0          ) xn / xn2 bf16      25,165,824
//   [25165824   ) q bf16             25,165,824   (aliased later by h1)
//   [50331648   ) k bf16             25,165,824   (h1)
//   [75497472   ) vT bf16            25,165,824   (h1)
//   [100663296  ) S/P bf16           67,108,864   (h1 head overlaps; dead by MLP)
//   [167772160  ) y bf16             25,165,824
//   [192937984  ) bf16 weights       14,155,776
// total: 207,093,760 bytes

typedef unsigned short u16;
typedef __bf16 bf16x8 __attribute__((ext_vector_type(8)));
typedef float  f32x4  __attribute__((ext_vector_type(4)));
typedef int    i32x4  __attribute__((ext_vector_type(4)));
typedef u16    u16x4  __attribute__((ext_vector_type(4)));

__device__ __forceinline__ u16 f2b(float f) {
    __hip_bfloat16 h = __float2bfloat16(f);
    return *reinterpret_cast<u16*>(&h);
}
__device__ __forceinline__ float b2f(u16 u) {
    unsigned int x = ((unsigned int)u) << 16;
    return __uint_as_float(x);
}

// ---------------- transpose + cast fp32 -> bf16 -----------------
// in: [R][Cc] fp32, out: [Cc][R] bf16
__global__ __launch_bounds__(256) void transpose_cast(const float* __restrict__ in,
                                                      u16* __restrict__ out,
                                                      int R, int Cc) {
    __shared__ float tile[32][33];
    int c0 = blockIdx.x * 32, r0 = blockIdx.y * 32;
    int tx = threadIdx.x, ty = threadIdx.y;
    for (int i = ty; i < 32; i += 8)
        tile[i][tx] = in[(long)(r0 + i) * Cc + c0 + tx];
    __syncthreads();
    for (int i = ty; i < 32; i += 8)
        out[(long)(c0 + i) * R + r0 + tx] = f2b(tile[tx][i]);
}

// ---------------- layernorm fp32 -> bf16 -----------------
__global__ __launch_bounds__(256) void ln_kernel(const float* __restrict__ x,
                                                 const float* __restrict__ g,
                                                 const float* __restrict__ b,
                                                 u16* __restrict__ out) {
    const int C = 768;
    long row = blockIdx.x;
    const float* xr = x + row * C;
    int t = threadIdx.x;
    float v0 = xr[t], v1 = xr[t + 256], v2 = xr[t + 512];
    float s = v0 + v1 + v2;
    float sq = v0 * v0 + v1 * v1 + v2 * v2;
#pragma unroll
    for (int o = 32; o; o >>= 1) {
        s += __shfl_xor(s, o);
        sq += __shfl_xor(sq, o);
    }
    __shared__ float ss[4], sq2[4];
    int wv = t >> 6;
    if ((t & 63) == 0) { ss[wv] = s; sq2[wv] = sq; }
    __syncthreads();
    s = ss[0] + ss[1] + ss[2] + ss[3];
    sq = sq2[0] + sq2[1] + sq2[2] + sq2[3];
    float mu = s * (1.0f / 768.0f);
    float var = sq * (1.0f / 768.0f) - mu * mu;
    float rs = rsqrtf(var + 1e-5f);
    u16* orow = out + row * C;
    orow[t]       = f2b((v0 - mu) * rs * g[t]       + b[t]);
    orow[t + 256] = f2b((v1 - mu) * rs * g[t + 256] + b[t + 256]);
    orow[t + 512] = f2b((v2 - mu) * rs * g[t + 512] + b[t + 512]);
}

// ---------------- causal softmax over bf16 scores, in place -----------------
// S: [8*2048][2048] bf16. Row r: batch r>>11, t = r&2047. cols > t -> 0.
__global__ __launch_bounds__(256) void softmax_causal(u16* __restrict__ S) {
    const int T = 2048;
    long row = blockIdx.x;
    int t = (int)(row & (T - 1));
    u16* p = S + row * T;
    int tid = threadIdx.x;
    float v[8];
    float mx = -3.0e38f;
#pragma unroll
    for (int j = 0; j < 8; j++) {
        int col = tid + j * 256;
        v[j] = (col <= t) ? b2f(p[col]) : -3.0e38f;
        mx = fmaxf(mx, v[j]);
    }
#pragma unroll
    for (int o = 32; o; o >>= 1) mx = fmaxf(mx, __shfl_xor(mx, o));
    __shared__ float sm[4], ssum[4];
    int wv = tid >> 6;
    if ((tid & 63) == 0) sm[wv] = mx;
    __syncthreads();
    mx = fmaxf(fmaxf(sm[0], sm[1]), fmaxf(sm[2], sm[3]));
    float s = 0.0f;
#pragma unroll
    for (int j = 0; j < 8; j++) {
        int col = tid + j * 256;
        float e = (col <= t) ? expf(v[j] - mx) : 0.0f;
        v[j] = e;
        s += e;
    }
#pragma unroll
    for (int o = 32; o; o >>= 1) s += __shfl_xor(s, o);
    if ((tid & 63) == 0) ssum[wv] = s;
    __syncthreads();
    s = ssum[0] + ssum[1] + ssum[2] + ssum[3];
    float inv = 1.0f / s;
#pragma unroll
    for (int j = 0; j < 8; j++) {
        int col = tid + j * 256;
        p[col] = f2b(v[j] * inv);
    }
}

// ---------------- bf16 GEMM, B given transposed: C[M,N] = A[M,K] @ Bt[N,K]^T -------------
// EPI: 0 = bf16 store (scaled)
//      1 = bf16 transposed store out[n][m] (scaled)
//      2 = bf16 gelu(acc + bias[n])
//      3 = f32 store resid[m][n] + acc + bias[n]
// CAUSAL: 0 none; 1 early-exit tiles with n0 >= m0+BM; 2 K-loop limited to m0+BM
#define BM 64
#define BN 64
#define BKT 64

template <int EPI, int CAUSAL>
__global__ __launch_bounds__(256) void gemm_bt(const u16* __restrict__ A,
                                               const u16* __restrict__ Bt,
                                               void* __restrict__ Out,
                                               const float* __restrict__ bias,
                                               const float* __restrict__ resid,
                                               int M, int N, int K,
                                               int lda, int ldb, int ldo,
                                               long long sA, long long sB, long long sO,
                                               float scale) {
    int bz = blockIdx.z;
    A += (long)bz * sA;
    Bt += (long)bz * sB;
    long obase = (long)bz * sO;

    int m0 = blockIdx.y * BM, n0 = blockIdx.x * BN;
    if (CAUSAL == 1 && n0 >= m0 + BM) return;
    int kend = (CAUSAL == 2) ? ((K < m0 + BM) ? K : (m0 + BM)) : K;

    __shared__ __align__(16) u16 As[BM][72];
    __shared__ __align__(16) u16 Bs[BN][72];

    int tid = threadIdx.x;
    int lane = tid & 63, l16 = lane & 15, quad = lane >> 4;
    int wave = tid >> 6;
    int wm = (wave >> 1) * 32, wn = (wave & 1) * 32;

    f32x4 acc[2][2] = {};

    int r0 = tid >> 3;           // 0..31
    int c0 = (tid & 7) * 8;      // 0..56

    for (int k0 = 0; k0 < kend; k0 += BKT) {
        *(i32x4*)(&As[r0][c0])      = *(const i32x4*)(A + (long)(m0 + r0) * lda + k0 + c0);
        *(i32x4*)(&As[r0 + 32][c0]) = *(const i32x4*)(A + (long)(m0 + r0 + 32) * lda + k0 + c0);
        *(i32x4*)(&Bs[r0][c0])      = *(const i32x4*)(Bt + (long)(n0 + r0) * ldb + k0 + c0);
        *(i32x4*)(&Bs[r0 + 32][c0]) = *(const i32x4*)(Bt + (long)(n0 + r0 + 32) * ldb + k0 + c0);
        __syncthreads();
#pragma unroll
        for (int kk = 0; kk < BKT; kk += 32) {
            bf16x8 a0 = *(const bf16x8*)(&As[wm + l16][kk + quad * 8]);
            bf16x8 a1 = *(const bf16x8*)(&As[wm + 16 + l16][kk + quad * 8]);
            bf16x8 b0 = *(const bf16x8*)(&Bs[wn + l16][kk + quad * 8]);
            bf16x8 b1 = *(const bf16x8*)(&Bs[wn + 16 + l16][kk + quad * 8]);
            acc[0][0] = __builtin_amdgcn_mfma_f32_16x16x32_bf16(a0, b0, acc[0][0], 0, 0, 0);
            acc[0][1] = __builtin_amdgcn_mfma_f32_16x16x32_bf16(a0, b1, acc[0][1], 0, 0, 0);
            acc[1][0] = __builtin_amdgcn_mfma_f32_16x16x32_bf16(a1, b0, acc[1][0], 0, 0, 0);
            acc[1][1] = __builtin_amdgcn_mfma_f32_16x16x32_bf16(a1, b1, acc[1][1], 0, 0, 0);
        }
        __syncthreads();
    }

#pragma unroll
    for (int mt = 0; mt < 2; ++mt)
#pragma unroll
        for (int nt = 0; nt < 2; ++nt) {
            int col = n0 + wn + nt * 16 + l16;
            int rbase = m0 + wm + mt * 16 + quad * 4;
            f32x4 a = acc[mt][nt];
            if (EPI == 0) {
                u16* o = (u16*)Out + obase;
#pragma unroll
                for (int r = 0; r < 4; r++)
                    o[(long)(rbase + r) * ldo + col] = f2b(a[r] * scale);
            } else if (EPI == 1) {
                u16* o = (u16*)Out + obase;
                u16x4 pk;
#pragma unroll
                for (int r = 0; r < 4; r++) pk[r] = f2b(a[r] * scale);
                *(u16x4*)(o + (long)col * ldo + rbase) = pk;
            } else if (EPI == 2) {
                u16* o = (u16*)Out + obase;
                float bv = bias[col];
#pragma unroll
                for (int r = 0; r < 4; r++) {
                    float v = a[r] + bv;
                    float ge = 0.5f * v * (1.0f + erff(v * 0.70710678118f));
                    o[(long)(rbase + r) * ldo + col] = f2b(ge);
                }
            } else {
                float* o = (float*)Out + obase;
                float bv = bias[col];
#pragma unroll
                for (int r = 0; r < 4; r++) {
                    long idx = (long)(rbase + r) * ldo + col;
                    o[idx] = resid[idx] + a[r] + bv;
                }
            }
        }
}

extern "C" void kernel_launch(void* const* d_in, const int* in_sizes, int n_in,
                              void* d_out, int out_size, void* d_ws, size_t ws_size,
                              hipStream_t stream) {
    (void)in_sizes; (void)n_in; (void)out_size; (void)ws_size;
    const float* x   = (const float*)d_in[0];
    const float* Wq  = (const float*)d_in[1];
    const float* Wk  = (const float*)d_in[2];
    const float* Wv  = (const float*)d_in[3];
    const float* Wp  = (const float*)d_in[4];
    const float* bp  = (const float*)d_in[5];
    const float* g1  = (const float*)d_in[6];
    const float* b1  = (const float*)d_in[7];
    const float* g2  = (const float*)d_in[8];
    const float* b2  = (const float*)d_in[9];
    const float* W1  = (const float*)d_in[10];
    const float* bm1 = (const float*)d_in[11];
    const float* W2  = (const float*)d_in[12];
    const float* bm2 = (const float*)d_in[13];
    float* out = (float*)d_out;

    const int Bn = 8, T = 2048, C = 768, F = 3072;
    const int M = Bn * T; // 16384

    char* ws = (char*)d_ws;
    u16* xn = (u16*)(ws);
    u16* q  = (u16*)(ws + 25165824);
    u16* kb = (u16*)(ws + 50331648);
    u16* vT = (u16*)(ws + 75497472);
    u16* S  = (u16*)(ws + 100663296);
    u16* y  = (u16*)(ws + 167772160);
    u16* h1 = (u16*)(ws + 25165824);   // aliases q/k/vT/S-head, all dead by MLP
    u16* wgt = (u16*)(ws + 192937984);
    u16* Wqt = wgt;
    u16* Wkt = Wqt + 589824;
    u16* Wvt = Wkt + 589824;
    u16* Wpt = Wvt + 589824;
    u16* W1t = Wpt + 589824;            // [3072][768]
    u16* W2t = W1t + (long)C * F;       // [768][3072]

    dim3 tb(32, 8);
    hipLaunchKernelGGL(transpose_cast, dim3(C / 32, C / 32), tb, 0, stream, Wq, Wqt, C, C);
    hipLaunchKernelGGL(transpose_cast, dim3(C / 32, C / 32), tb, 0, stream, Wk, Wkt, C, C);
    hipLaunchKernelGGL(transpose_cast, dim3(C / 32, C / 32), tb, 0, stream, Wv, Wvt, C, C);
    hipLaunchKernelGGL(transpose_cast, dim3(C / 32, C / 32), tb, 0, stream, Wp, Wpt, C, C);
    hipLaunchKernelGGL(transpose_cast, dim3(F / 32, C / 32), tb, 0, stream, W1, W1t, C, F);
    hipLaunchKernelGGL(transpose_cast, dim3(C / 32, F / 32), tb, 0, stream, W2, W2t, F, C);

    // LN1: xn = LN(x, g1, b1)
    hipLaunchKernelGGL(ln_kernel, dim3(M), dim3(256), 0, stream, x, g1, b1, xn);

    // q = xn@Wq, k = xn@Wk (bf16 out)
    hipLaunchKernelGGL((gemm_bt<0, 0>), dim3(C / BN, M / BM, 1), dim3(256), 0, stream,
                       xn, Wqt, (void*)q, nullptr, nullptr, M, C, C, C, C, C, 0LL, 0LL, 0LL, 1.0f);
    hipLaunchKernelGGL((gemm_bt<0, 0>), dim3(C / BN, M / BM, 1), dim3(256), 0, stream,
                       xn, Wkt, (void*)kb, nullptr, nullptr, M, C, C, C, C, C, 0LL, 0LL, 0LL, 1.0f);
    // vT[b][c][t] = (xn@Wv)[b][t][c]  (transposed epilogue, batched)
    hipLaunchKernelGGL((gemm_bt<1, 0>), dim3(C / BN, T / BM, Bn), dim3(256), 0, stream,
                       xn, Wvt, (void*)vT, nullptr, nullptr, T, C, C, C, C, T,
                       (long long)T * C, 0LL, (long long)C * T, 1.0f);

    // S = scale * q @ k^T (causal tile pruning), bf16
    float scl = 1.0f / sqrtf((float)C);
    hipLaunchKernelGGL((gemm_bt<0, 1>), dim3(T / BN, T / BM, Bn), dim3(256), 0, stream,
                       q, kb, (void*)S, nullptr, nullptr, T, T, C, C, C, T,
                       (long long)T * C, (long long)T * C, (long long)T * T, scl);

    // causal softmax in place
    hipLaunchKernelGGL(softmax_causal, dim3(M), dim3(256), 0, stream, S);

    // y = P @ V  (Bt = vT, K limited to m0+64)
    hipLaunchKernelGGL((gemm_bt<0, 2>), dim3(C / BN, T / BM, Bn), dim3(256), 0, stream,
                       S, vT, (void*)y, nullptr, nullptr, T, C, T, T, T, C,
                       (long long)T * T, (long long)C * T, (long long)T * C, 1.0f);

    // out = x + y@Wp + bp   (fp32)
    hipLaunchKernelGGL((gemm_bt<3, 0>), dim3(C / BN, M / BM, 1), dim3(256), 0, stream,
                       y, Wpt, (void*)out, bp, x, M, C, C, C, C, C, 0LL, 0LL, 0LL, 1.0f);

    // LN2: xn2 = LN(out, g2, b2)
    hipLaunchKernelGGL(ln_kernel, dim3(M), dim3(256), 0, stream, out, g2, b2, xn);

    // h1 = gelu(xn2@W1 + bm1)  bf16
    hipLaunchKernelGGL((gemm_bt<2, 0>), dim3(F / BN, M / BM, 1), dim3(256), 0, stream,
                       xn, W1t, (void*)h1, bm1, nullptr, M, F, C, C, C, F, 0LL, 0LL, 0LL, 1.0f);

    // out = out + h1@W2 + bm2
    hipLaunchKernelGGL((gemm_bt<3, 0>), dim3(C / BN, M / BM, 1), dim3(256), 0, stream,
                       h1, W2t, (void*)out, bm2, out, M, C, F, F, F, C, 0LL, 0LL, 0LL, 1.0f);
}

// Round 2
// 745.391 us; speedup vs baseline: 1.2526x; 1.2526x over previous
//
#include <hip/hip_runtime.h>
#include <hip/hip_bf16.h>

// Transformer block: x:[8,2048,768] fp32. All GEMMs in bf16 MFMA (fp32 acc).
// m97-style GEMM: 128x128x64 tiles, global_load_lds dwordx4 staging, XOR bank swizzle.
// Workspace layout (bytes):
//   [0          ) xn / xn2 bf16      25,165,824
//   [25165824   ) q bf16             25,165,824   (aliased later by h1)
//   [50331648   ) k bf16             25,165,824   (h1)
//   [75497472   ) vT bf16            25,165,824   (h1)
//   [100663296  ) S/P bf16           67,108,864   (h1 head overlaps; dead by MLP)
//   [167772160  ) y bf16             25,165,824
//   [192937984  ) bf16 weights       14,155,776
// total: 207,093,760 bytes

typedef unsigned short u16;
typedef __bf16 bf16x8 __attribute__((ext_vector_type(8)));
typedef float  f32x4  __attribute__((ext_vector_type(4)));
typedef int    i32x4  __attribute__((ext_vector_type(4)));
typedef u16    u16x4  __attribute__((ext_vector_type(4)));

__device__ __forceinline__ u16 f2b(float f) {
    __hip_bfloat16 h = __float2bfloat16(f);
    return *reinterpret_cast<u16*>(&h);
}
__device__ __forceinline__ float b2f(u16 u) {
    unsigned int x = ((unsigned int)u) << 16;
    return __uint_as_float(x);
}

// async 16B global -> LDS. lds base must be wave-uniform; HW adds lane*16.
__device__ __forceinline__ void stage16(u16* lds_base_uniform, const u16* g, int lane) {
#if __has_builtin(__builtin_amdgcn_global_load_lds)
    __builtin_amdgcn_global_load_lds(
        (const __attribute__((address_space(1))) void*)g,
        (__attribute__((address_space(3))) void*)lds_base_uniform,
        16, 0, 0);
#else
    *(i32x4*)(lds_base_uniform + lane * 8) = *(const i32x4*)g;
#endif
}

// ---------------- transpose + cast fp32 -> bf16 -----------------
__global__ __launch_bounds__(256) void transpose_cast(const float* __restrict__ in,
                                                      u16* __restrict__ out,
                                                      int R, int Cc) {
    __shared__ float tile[32][33];
    int c0 = blockIdx.x * 32, r0 = blockIdx.y * 32;
    int tx = threadIdx.x, ty = threadIdx.y;
    for (int i = ty; i < 32; i += 8)
        tile[i][tx] = in[(long)(r0 + i) * Cc + c0 + tx];
    __syncthreads();
    for (int i = ty; i < 32; i += 8)
        out[(long)(c0 + i) * R + r0 + tx] = f2b(tile[tx][i]);
}

// ---------------- layernorm fp32 -> bf16 -----------------
__global__ __launch_bounds__(256) void ln_kernel(const float* __restrict__ x,
                                                 const float* __restrict__ g,
                                                 const float* __restrict__ b,
                                                 u16* __restrict__ out) {
    const int C = 768;
    long row = blockIdx.x;
    const float* xr = x + row * C;
    int t = threadIdx.x;
    float v0 = xr[t], v1 = xr[t + 256], v2 = xr[t + 512];
    float s = v0 + v1 + v2;
    float sq = v0 * v0 + v1 * v1 + v2 * v2;
#pragma unroll
    for (int o = 32; o; o >>= 1) {
        s += __shfl_xor(s, o);
        sq += __shfl_xor(sq, o);
    }
    __shared__ float ss[4], sq2[4];
    int wv = t >> 6;
    if ((t & 63) == 0) { ss[wv] = s; sq2[wv] = sq; }
    __syncthreads();
    s = ss[0] + ss[1] + ss[2] + ss[3];
    sq = sq2[0] + sq2[1] + sq2[2] + sq2[3];
    float mu = s * (1.0f / 768.0f);
    float var = sq * (1.0f / 768.0f) - mu * mu;
    float rs = rsqrtf(var + 1e-5f);
    u16* orow = out + row * C;
    orow[t]       = f2b((v0 - mu) * rs * g[t]       + b[t]);
    orow[t + 256] = f2b((v1 - mu) * rs * g[t + 256] + b[t + 256]);
    orow[t + 512] = f2b((v2 - mu) * rs * g[t + 512] + b[t + 512]);
}

// ---------------- causal softmax over bf16 scores, in place -----------------
__global__ __launch_bounds__(256) void softmax_causal(u16* __restrict__ S) {
    const int T = 2048;
    long row = blockIdx.x;
    int t = (int)(row & (T - 1));
    u16* p = S + row * T;
    int tid = threadIdx.x;
    float v[8];
    float mx = -3.0e38f;
#pragma unroll
    for (int j = 0; j < 8; j++) {
        int col = tid + j * 256;
        v[j] = (col <= t) ? b2f(p[col]) : -3.0e38f;
        mx = fmaxf(mx, v[j]);
    }
#pragma unroll
    for (int o = 32; o; o >>= 1) mx = fmaxf(mx, __shfl_xor(mx, o));
    __shared__ float sm[4], ssum[4];
    int wv = tid >> 6;
    if ((tid & 63) == 0) sm[wv] = mx;
    __syncthreads();
    mx = fmaxf(fmaxf(sm[0], sm[1]), fmaxf(sm[2], sm[3]));
    float s = 0.0f;
#pragma unroll
    for (int j = 0; j < 8; j++) {
        int col = tid + j * 256;
        float e = (col <= t) ? expf(v[j] - mx) : 0.0f;
        v[j] = e;
        s += e;
    }
#pragma unroll
    for (int o = 32; o; o >>= 1) s += __shfl_xor(s, o);
    if ((tid & 63) == 0) ssum[wv] = s;
    __syncthreads();
    s = ssum[0] + ssum[1] + ssum[2] + ssum[3];
    float inv = 1.0f / s;
#pragma unroll
    for (int j = 0; j < 8; j++) {
        int col = tid + j * 256;
        p[col] = f2b(v[j] * inv);
    }
}

// ---------------- bf16 GEMM (m97 structure): C[M,N] = A[M,K] @ Bt[N,K]^T -------------
// 128x128 tile, BK=64, 4 waves in 2x2, each wave 4x4 of 16x16x32 MFMA.
// LDS: As/Bs [128][64] bf16 unpadded (global_load_lds layout), XOR-swizzled chunks:
//   chunk c (8 shorts) of row r lives at slot c ^ (r&7).
// EPI: 0 bf16 store (scaled); 1 bf16 transposed store out[n][m]; 2 bf16 gelu(acc+bias);
//      3 f32 resid[m][n] + acc + bias[n]
// CAUSAL: 0 none; 1 skip tiles n0 >= m0+128; 2 K-loop limited to m0+128
#define BM 128
#define BN 128
#define BKT 64

template <int EPI, int CAUSAL>
__global__ __launch_bounds__(256) void gemm_bt(const u16* __restrict__ A,
                                               const u16* __restrict__ Bt,
                                               void* __restrict__ Out,
                                               const float* __restrict__ bias,
                                               const float* __restrict__ resid,
                                               int M, int N, int K,
                                               int lda, int ldb, int ldo,
                                               long long sA, long long sB, long long sO,
                                               float scale) {
    int bz = blockIdx.z;
    A += (long)bz * sA;
    Bt += (long)bz * sB;
    long obase = (long)bz * sO;

    int m0 = blockIdx.y * BM, n0 = blockIdx.x * BN;
    if (CAUSAL == 1 && n0 >= m0 + BM) return;
    int kend = (CAUSAL == 2) ? ((K < m0 + BM) ? K : (m0 + BM)) : K;

    // 128 rows x 64 cols bf16 = 16 KB each
    __shared__ __align__(16) u16 As[128 * 64];
    __shared__ __align__(16) u16 Bs[128 * 64];

    int tid = threadIdx.x;
    int lane = tid & 63, l16 = lane & 15, quad = lane >> 4;
    int w = tid >> 6;
    int wm = (w >> 1) * 64, wn = (w & 1) * 64;

    f32x4 acc[4][4] = {};

    for (int k0 = 0; k0 < kend; k0 += BKT) {
        // stage A and B tiles: 1024 chunks each, 4 per thread per tile
#pragma unroll
        for (int i = 0; i < 4; i++) {
            int ebase = i * 256 + w * 64;         // wave-uniform chunk base
            int e = ebase + lane;
            int row = e >> 3;
            int gc = (e & 7) ^ (row & 7);         // XOR swizzle: fetch permuted chunk
            stage16(As + ebase * 8, A + (long)(m0 + row) * lda + k0 + gc * 8, lane);
            stage16(Bs + ebase * 8, Bt + (long)(n0 + row) * ldb + k0 + gc * 8, lane);
        }
        __syncthreads();
#pragma unroll
        for (int kk = 0; kk < BKT; kk += 32) {
            int cbase = (kk >> 3) + quad;         // chunk col index of this lane's fragment
            int slot = (cbase ^ (l16 & 7)) << 3;  // swizzled short offset within row
            bf16x8 af[4], bf[4];
#pragma unroll
            for (int mt = 0; mt < 4; mt++)
                af[mt] = *(const bf16x8*)(As + (wm + mt * 16 + l16) * 64 + slot);
#pragma unroll
            for (int nt = 0; nt < 4; nt++)
                bf[nt] = *(const bf16x8*)(Bs + (wn + nt * 16 + l16) * 64 + slot);
#pragma unroll
            for (int mt = 0; mt < 4; mt++)
#pragma unroll
                for (int nt = 0; nt < 4; nt++)
                    acc[mt][nt] = __builtin_amdgcn_mfma_f32_16x16x32_bf16(af[mt], bf[nt], acc[mt][nt], 0, 0, 0);
        }
        __syncthreads();
    }

#pragma unroll
    for (int mt = 0; mt < 4; ++mt)
#pragma unroll
        for (int nt = 0; nt < 4; ++nt) {
            int col = n0 + wn + nt * 16 + l16;
            int rbase = m0 + wm + mt * 16 + quad * 4;
            f32x4 a = acc[mt][nt];
            if (EPI == 0) {
                u16* o = (u16*)Out + obase;
#pragma unroll
                for (int r = 0; r < 4; r++)
                    o[(long)(rbase + r) * ldo + col] = f2b(a[r] * scale);
            } else if (EPI == 1) {
                u16* o = (u16*)Out + obase;
                u16x4 pk;
#pragma unroll
                for (int r = 0; r < 4; r++) pk[r] = f2b(a[r] * scale);
                *(u16x4*)(o + (long)col * ldo + rbase) = pk;
            } else if (EPI == 2) {
                u16* o = (u16*)Out + obase;
                float bv = bias[col];
#pragma unroll
                for (int r = 0; r < 4; r++) {
                    float v = a[r] + bv;
                    float ge = 0.5f * v * (1.0f + erff(v * 0.70710678118f));
                    o[(long)(rbase + r) * ldo + col] = f2b(ge);
                }
            } else {
                float* o = (float*)Out + obase;
                float bv = bias[col];
#pragma unroll
                for (int r = 0; r < 4; r++) {
                    long idx = (long)(rbase + r) * ldo + col;
                    o[idx] = resid[idx] + a[r] + bv;
                }
            }
        }
}

extern "C" void kernel_launch(void* const* d_in, const int* in_sizes, int n_in,
                              void* d_out, int out_size, void* d_ws, size_t ws_size,
                              hipStream_t stream) {
    (void)in_sizes; (void)n_in; (void)out_size; (void)ws_size;
    const float* x   = (const float*)d_in[0];
    const float* Wq  = (const float*)d_in[1];
    const float* Wk  = (const float*)d_in[2];
    const float* Wv  = (const float*)d_in[3];
    const float* Wp  = (const float*)d_in[4];
    const float* bp  = (const float*)d_in[5];
    const float* g1  = (const float*)d_in[6];
    const float* b1  = (const float*)d_in[7];
    const float* g2  = (const float*)d_in[8];
    const float* b2  = (const float*)d_in[9];
    const float* W1  = (const float*)d_in[10];
    const float* bm1 = (const float*)d_in[11];
    const float* W2  = (const float*)d_in[12];
    const float* bm2 = (const float*)d_in[13];
    float* out = (float*)d_out;

    const int Bn = 8, T = 2048, C = 768, F = 3072;
    const int M = Bn * T; // 16384

    char* ws = (char*)d_ws;
    u16* xn = (u16*)(ws);
    u16* q  = (u16*)(ws + 25165824);
    u16* kb = (u16*)(ws + 50331648);
    u16* vT = (u16*)(ws + 75497472);
    u16* S  = (u16*)(ws + 100663296);
    u16* y  = (u16*)(ws + 167772160);
    u16* h1 = (u16*)(ws + 25165824);   // aliases q/k/vT/S-head, all dead by MLP
    u16* wgt = (u16*)(ws + 192937984);
    u16* Wqt = wgt;
    u16* Wkt = Wqt + 589824;
    u16* Wvt = Wkt + 589824;
    u16* Wpt = Wvt + 589824;
    u16* W1t = Wpt + 589824;            // [3072][768]
    u16* W2t = W1t + (long)C * F;       // [768][3072]

    dim3 tb(32, 8);
    hipLaunchKernelGGL(transpose_cast, dim3(C / 32, C / 32), tb, 0, stream, Wq, Wqt, C, C);
    hipLaunchKernelGGL(transpose_cast, dim3(C / 32, C / 32), tb, 0, stream, Wk, Wkt, C, C);
    hipLaunchKernelGGL(transpose_cast, dim3(C / 32, C / 32), tb, 0, stream, Wv, Wvt, C, C);
    hipLaunchKernelGGL(transpose_cast, dim3(C / 32, C / 32), tb, 0, stream, Wp, Wpt, C, C);
    hipLaunchKernelGGL(transpose_cast, dim3(F / 32, C / 32), tb, 0, stream, W1, W1t, C, F);
    hipLaunchKernelGGL(transpose_cast, dim3(C / 32, F / 32), tb, 0, stream, W2, W2t, F, C);

    // LN1
    hipLaunchKernelGGL(ln_kernel, dim3(M), dim3(256), 0, stream, x, g1, b1, xn);

    // q = xn@Wq, k = xn@Wk (bf16 out)
    hipLaunchKernelGGL((gemm_bt<0, 0>), dim3(C / BN, M / BM, 1), dim3(256), 0, stream,
                       xn, Wqt, (void*)q, nullptr, nullptr, M, C, C, C, C, C, 0LL, 0LL, 0LL, 1.0f);
    hipLaunchKernelGGL((gemm_bt<0, 0>), dim3(C / BN, M / BM, 1), dim3(256), 0, stream,
                       xn, Wkt, (void*)kb, nullptr, nullptr, M, C, C, C, C, C, 0LL, 0LL, 0LL, 1.0f);
    // vT[b][c][t] = (xn@Wv)[b][t][c]
    hipLaunchKernelGGL((gemm_bt<1, 0>), dim3(C / BN, T / BM, Bn), dim3(256), 0, stream,
                       xn, Wvt, (void*)vT, nullptr, nullptr, T, C, C, C, C, T,
                       (long long)T * C, 0LL, (long long)C * T, 1.0f);

    // S = scale * q @ k^T (causal tile pruning), bf16
    float scl = 1.0f / sqrtf((float)C);
    hipLaunchKernelGGL((gemm_bt<0, 1>), dim3(T / BN, T / BM, Bn), dim3(256), 0, stream,
                       q, kb, (void*)S, nullptr, nullptr, T, T, C, C, C, T,
                       (long long)T * C, (long long)T * C, (long long)T * T, scl);

    // causal softmax in place
    hipLaunchKernelGGL(softmax_causal, dim3(M), dim3(256), 0, stream, S);

    // y = P @ V  (Bt = vT, K limited to m0+128)
    hipLaunchKernelGGL((gemm_bt<0, 2>), dim3(C / BN, T / BM, Bn), dim3(256), 0, stream,
                       S, vT, (void*)y, nullptr, nullptr, T, C, T, T, T, C,
                       (long long)T * T, (long long)C * T, (long long)T * C, 1.0f);

    // out = x + y@Wp + bp   (fp32)
    hipLaunchKernelGGL((gemm_bt<3, 0>), dim3(C / BN, M / BM, 1), dim3(256), 0, stream,
                       y, Wpt, (void*)out, bp, x, M, C, C, C, C, C, 0LL, 0LL, 0LL, 1.0f);

    // LN2
    hipLaunchKernelGGL(ln_kernel, dim3(M), dim3(256), 0, stream, out, g2, b2, xn);

    // h1 = gelu(xn2@W1 + bm1)  bf16
    hipLaunchKernelGGL((gemm_bt<2, 0>), dim3(F / BN, M / BM, 1), dim3(256), 0, stream,
                       xn, W1t, (void*)h1, bm1, nullptr, M, F, C, C, C, F, 0LL, 0LL, 0LL, 1.0f);

    // out = out + h1@W2 + bm2
    hipLaunchKernelGGL((gemm_bt<3, 0>), dim3(C / BN, M / BM, 1), dim3(256), 0, stream,
                       h1, W2t, (void*)out, bm2, out, M, C, F, F, F, C, 0LL, 0LL, 0LL, 1.0f);
}

// Round 3
// 695.777 us; speedup vs baseline: 1.3420x; 1.0713x over previous
//
#include <hip/hip_runtime.h>
#include <hip/hip_bf16.h>

// Transformer block: x:[8,2048,768] fp32. All GEMMs in bf16 MFMA (fp32 acc).
// m97-style GEMM: 128x128x64 tiles, global_load_lds dwordx4, XOR bank swizzle,
// XCD-aware block swizzle (contiguous x-major chunk per XCD).
// Workspace layout (bytes):
//   [0          ) xn / xn2 bf16        25,165,824
//   [25165824   ) QK bf16 [16384][1536] 50,331,648   (aliased later by h1)
//   [75497472   ) vT bf16 [8][768][2048] 25,165,824  (h1)
//   [100663296  ) S/P bf16 [8][2048][2048] 67,108,864 (h1 head overlaps; dead by MLP)
//   [167772160  ) y bf16               25,165,824
//   [192937984  ) bf16 weights         14,155,776
// total: 207,093,760 bytes

typedef unsigned short u16;
typedef __bf16 bf16x8 __attribute__((ext_vector_type(8)));
typedef float  f32x4  __attribute__((ext_vector_type(4)));
typedef int    i32x4  __attribute__((ext_vector_type(4)));
typedef u16    u16x4  __attribute__((ext_vector_type(4)));

__device__ __forceinline__ u16 f2b(float f) {
    __hip_bfloat16 h = __float2bfloat16(f);
    return *reinterpret_cast<u16*>(&h);
}
__device__ __forceinline__ float b2f(u16 u) {
    unsigned int x = ((unsigned int)u) << 16;
    return __uint_as_float(x);
}

// async 16B global -> LDS. lds base must be wave-uniform; HW adds lane*16.
__device__ __forceinline__ void stage16(u16* lds_base_uniform, const u16* g, int lane) {
#if __has_builtin(__builtin_amdgcn_global_load_lds)
    __builtin_amdgcn_global_load_lds(
        (const __attribute__((address_space(1))) void*)g,
        (__attribute__((address_space(3))) void*)lds_base_uniform,
        16, 0, 0);
#else
    *(i32x4*)(lds_base_uniform + lane * 8) = *(const i32x4*)g;
#endif
}

// ---------------- transpose + cast fp32 -> bf16 -----------------
__global__ __launch_bounds__(256) void transpose_cast(const float* __restrict__ in,
                                                      u16* __restrict__ out,
                                                      int R, int Cc) {
    __shared__ float tile[32][33];
    int c0 = blockIdx.x * 32, r0 = blockIdx.y * 32;
    int tx = threadIdx.x, ty = threadIdx.y;
    for (int i = ty; i < 32; i += 8)
        tile[i][tx] = in[(long)(r0 + i) * Cc + c0 + tx];
    __syncthreads();
    for (int i = ty; i < 32; i += 8)
        out[(long)(c0 + i) * R + r0 + tx] = f2b(tile[tx][i]);
}

// ---------------- layernorm fp32 -> bf16 -----------------
__global__ __launch_bounds__(256) void ln_kernel(const float* __restrict__ x,
                                                 const float* __restrict__ g,
                                                 const float* __restrict__ b,
                                                 u16* __restrict__ out) {
    const int C = 768;
    long row = blockIdx.x;
    const float* xr = x + row * C;
    int t = threadIdx.x;
    float v0 = xr[t], v1 = xr[t + 256], v2 = xr[t + 512];
    float s = v0 + v1 + v2;
    float sq = v0 * v0 + v1 * v1 + v2 * v2;
#pragma unroll
    for (int o = 32; o; o >>= 1) {
        s += __shfl_xor(s, o);
        sq += __shfl_xor(sq, o);
    }
    __shared__ float ss[4], sq2[4];
    int wv = t >> 6;
    if ((t & 63) == 0) { ss[wv] = s; sq2[wv] = sq; }
    __syncthreads();
    s = ss[0] + ss[1] + ss[2] + ss[3];
    sq = sq2[0] + sq2[1] + sq2[2] + sq2[3];
    float mu = s * (1.0f / 768.0f);
    float var = sq * (1.0f / 768.0f) - mu * mu;
    float rs = rsqrtf(var + 1e-5f);
    u16* orow = out + row * C;
    orow[t]       = f2b((v0 - mu) * rs * g[t]       + b[t]);
    orow[t + 256] = f2b((v1 - mu) * rs * g[t + 256] + b[t + 256]);
    orow[t + 512] = f2b((v2 - mu) * rs * g[t + 512] + b[t + 512]);
}

// ---------------- causal softmax over bf16 scores, in place -----------------
// Only the live region [0, ((t>>7)+1)<<7) is read/written; PV's K-limit reads exactly that.
__global__ __launch_bounds__(256) void softmax_causal(u16* __restrict__ S) {
    const int T = 2048;
    long row = blockIdx.x;
    int t = (int)(row & (T - 1));
    int ncols = ((t >> 7) + 1) << 7;   // multiple of 128, > t
    u16* p = S + row * T;
    int tid = threadIdx.x;
    float v[8];
    float mx = -3.0e38f;
#pragma unroll
    for (int j = 0; j < 8; j++) {
        int col = tid + j * 256;
        v[j] = (col <= t) ? b2f(p[col]) : -3.0e38f;
        mx = fmaxf(mx, v[j]);
        if (col >= ncols) break;  // uniform across block? no—per-thread; bounded by unroll
    }
#pragma unroll
    for (int o = 32; o; o >>= 1) mx = fmaxf(mx, __shfl_xor(mx, o));
    __shared__ float sm[4], ssum[4];
    int wv = tid >> 6;
    if ((tid & 63) == 0) sm[wv] = mx;
    __syncthreads();
    mx = fmaxf(fmaxf(sm[0], sm[1]), fmaxf(sm[2], sm[3]));
    float s = 0.0f;
#pragma unroll
    for (int j = 0; j < 8; j++) {
        int col = tid + j * 256;
        if (col >= ncols) break;
        float e = (col <= t) ? expf(v[j] - mx) : 0.0f;
        v[j] = e;
        s += e;
    }
#pragma unroll
    for (int o = 32; o; o >>= 1) s += __shfl_xor(s, o);
    if ((tid & 63) == 0) ssum[wv] = s;
    __syncthreads();
    s = ssum[0] + ssum[1] + ssum[2] + ssum[3];
    float inv = 1.0f / s;
#pragma unroll
    for (int j = 0; j < 8; j++) {
        int col = tid + j * 256;
        if (col >= ncols) break;
        p[col] = f2b(v[j] * inv);
    }
}

// ---------------- bf16 GEMM (m97 structure): C[M,N] = A[M,K] @ Bt[N,K]^T -------------
// 128x128 tile, BK=64, 4 waves in 2x2, each wave 4x4 of 16x16x32 MFMA.
// LDS unpadded [128][64] (global_load_lds layout), XOR-swizzled chunks.
// XCD swizzle: linear block id -> contiguous x-major chunk per XCD (id%8).
// EPI: 0 bf16 store (scaled); 1 bf16 transposed store out[n][m]; 2 bf16 gelu(acc+bias);
//      3 f32 resid[m][n]+acc+bias[n]; 4 fused-QKV split (qk row-major ld 1536, v->vT)
// CAUSAL: 0 none; 1 skip tiles n0 >= m0+128; 2 K-loop limited to m0+128
#define BM 128
#define BN 128
#define BKT 64

template <int EPI, int CAUSAL>
__global__ __launch_bounds__(256) void gemm_bt(const u16* __restrict__ A,
                                               const u16* __restrict__ Bt,
                                               void* __restrict__ Out,
                                               void* __restrict__ Out2,
                                               const float* __restrict__ bias,
                                               const float* __restrict__ resid,
                                               int M, int N, int K,
                                               int lda, int ldb, int ldo,
                                               long long sA, long long sB, long long sO,
                                               float scale) {
    int bz = blockIdx.z;
    A += (long)bz * sA;
    Bt += (long)bz * sB;
    long obase = (long)bz * sO;

    // XCD-aware swizzle: HW round-robins linear id % 8 across XCDs; give each XCD
    // a contiguous x-major chunk so same-A-panel tiles share one L2.
    int gx = gridDim.x;
    int nblk = gx * gridDim.y;
    int lin = blockIdx.y * gx + blockIdx.x;
    int chunk = nblk >> 3;   // all our grids are %8 == 0
    int tile = (lin & 7) * chunk + (lin >> 3);
    int m0 = (tile / gx) * BM;
    int n0 = (tile % gx) * BN;

    if (CAUSAL == 1 && n0 >= m0 + BM) return;
    int kend = (CAUSAL == 2) ? ((K < m0 + BM) ? K : (m0 + BM)) : K;

    __shared__ __align__(16) u16 As[128 * 64];
    __shared__ __align__(16) u16 Bs[128 * 64];

    int tid = threadIdx.x;
    int lane = tid & 63, l16 = lane & 15, quad = lane >> 4;
    int w = tid >> 6;
    int wm = (w >> 1) * 64, wn = (w & 1) * 64;

    f32x4 acc[4][4] = {};

    for (int k0 = 0; k0 < kend; k0 += BKT) {
#pragma unroll
        for (int i = 0; i < 4; i++) {
            int ebase = i * 256 + w * 64;         // wave-uniform chunk base
            int e = ebase + lane;
            int row = e >> 3;
            int gc = (e & 7) ^ (row & 7);         // XOR swizzle: fetch permuted chunk
            stage16(As + ebase * 8, A + (long)(m0 + row) * lda + k0 + gc * 8, lane);
            stage16(Bs + ebase * 8, Bt + (long)(n0 + row) * ldb + k0 + gc * 8, lane);
        }
        __syncthreads();
#pragma unroll
        for (int kk = 0; kk < BKT; kk += 32) {
            int cbase = (kk >> 3) + quad;
            int slot = (cbase ^ (l16 & 7)) << 3;
            bf16x8 af[4], bf[4];
#pragma unroll
            for (int mt = 0; mt < 4; mt++)
                af[mt] = *(const bf16x8*)(As + (wm + mt * 16 + l16) * 64 + slot);
#pragma unroll
            for (int nt = 0; nt < 4; nt++)
                bf[nt] = *(const bf16x8*)(Bs + (wn + nt * 16 + l16) * 64 + slot);
#pragma unroll
            for (int mt = 0; mt < 4; mt++)
#pragma unroll
                for (int nt = 0; nt < 4; nt++)
                    acc[mt][nt] = __builtin_amdgcn_mfma_f32_16x16x32_bf16(af[mt], bf[nt], acc[mt][nt], 0, 0, 0);
        }
        __syncthreads();
    }

#pragma unroll
    for (int mt = 0; mt < 4; ++mt)
#pragma unroll
        for (int nt = 0; nt < 4; ++nt) {
            int col = n0 + wn + nt * 16 + l16;
            int rbase = m0 + wm + mt * 16 + quad * 4;
            f32x4 a = acc[mt][nt];
            if (EPI == 0) {
                u16* o = (u16*)Out + obase;
#pragma unroll
                for (int r = 0; r < 4; r++)
                    o[(long)(rbase + r) * ldo + col] = f2b(a[r] * scale);
            } else if (EPI == 1) {
                u16* o = (u16*)Out + obase;
                u16x4 pk;
#pragma unroll
                for (int r = 0; r < 4; r++) pk[r] = f2b(a[r] * scale);
                *(u16x4*)(o + (long)col * ldo + rbase) = pk;
            } else if (EPI == 2) {
                u16* o = (u16*)Out + obase;
                float bv = bias[col];
#pragma unroll
                for (int r = 0; r < 4; r++) {
                    float v = a[r] + bv;
                    float ge = 0.5f * v * (1.0f + erff(v * 0.70710678118f));
                    o[(long)(rbase + r) * ldo + col] = f2b(ge);
                }
            } else if (EPI == 3) {
                float* o = (float*)Out + obase;
                float bv = bias[col];
#pragma unroll
                for (int r = 0; r < 4; r++) {
                    long idx = (long)(rbase + r) * ldo + col;
                    o[idx] = resid[idx] + a[r] + bv;
                }
            } else { // EPI 4: fused QKV. col<1536 -> qk [M][1536]; else v -> vT[b][c][t]
                if (col < 1536) {
                    u16* o = (u16*)Out;
#pragma unroll
                    for (int r = 0; r < 4; r++)
                        o[(long)(rbase + r) * 1536 + col] = f2b(a[r]);
                } else {
                    u16* o = (u16*)Out2;
                    int b = rbase >> 11, t = rbase & 2047, c = col - 1536;
                    u16x4 pk;
#pragma unroll
                    for (int r = 0; r < 4; r++) pk[r] = f2b(a[r]);
                    *(u16x4*)(o + ((long)b * 768 + c) * 2048 + t) = pk;
                }
            }
        }
}

extern "C" void kernel_launch(void* const* d_in, const int* in_sizes, int n_in,
                              void* d_out, int out_size, void* d_ws, size_t ws_size,
                              hipStream_t stream) {
    (void)in_sizes; (void)n_in; (void)out_size; (void)ws_size;
    const float* x   = (const float*)d_in[0];
    const float* Wq  = (const float*)d_in[1];
    const float* Wk  = (const float*)d_in[2];
    const float* Wv  = (const float*)d_in[3];
    const float* Wp  = (const float*)d_in[4];
    const float* bp  = (const float*)d_in[5];
    const float* g1  = (const float*)d_in[6];
    const float* b1  = (const float*)d_in[7];
    const float* g2  = (const float*)d_in[8];
    const float* b2  = (const float*)d_in[9];
    const float* W1  = (const float*)d_in[10];
    const float* bm1 = (const float*)d_in[11];
    const float* W2  = (const float*)d_in[12];
    const float* bm2 = (const float*)d_in[13];
    float* out = (float*)d_out;

    const int Bn = 8, T = 2048, C = 768, F = 3072;
    const int M = Bn * T; // 16384

    char* ws = (char*)d_ws;
    u16* xn = (u16*)(ws);
    u16* QK = (u16*)(ws + 25165824);   // [16384][1536]: q | k
    u16* vT = (u16*)(ws + 75497472);   // [8][768][2048]
    u16* S  = (u16*)(ws + 100663296);  // [8][2048][2048]
    u16* y  = (u16*)(ws + 167772160);
    u16* h1 = (u16*)(ws + 25165824);   // aliases QK/vT/S-head, all dead by MLP
    u16* wgt = (u16*)(ws + 192937984);
    u16* Wqt = wgt;                     // [2304][768] fused qkv^T (q|k|v rows)
    u16* Wkt = Wqt + 589824;
    u16* Wvt = Wkt + 589824;
    u16* Wpt = Wvt + 589824;
    u16* W1t = Wpt + 589824;            // [3072][768]
    u16* W2t = W1t + (long)C * F;       // [768][3072]

    dim3 tb(32, 8);
    hipLaunchKernelGGL(transpose_cast, dim3(C / 32, C / 32), tb, 0, stream, Wq, Wqt, C, C);
    hipLaunchKernelGGL(transpose_cast, dim3(C / 32, C / 32), tb, 0, stream, Wk, Wkt, C, C);
    hipLaunchKernelGGL(transpose_cast, dim3(C / 32, C / 32), tb, 0, stream, Wv, Wvt, C, C);
    hipLaunchKernelGGL(transpose_cast, dim3(C / 32, C / 32), tb, 0, stream, Wp, Wpt, C, C);
    hipLaunchKernelGGL(transpose_cast, dim3(F / 32, C / 32), tb, 0, stream, W1, W1t, C, F);
    hipLaunchKernelGGL(transpose_cast, dim3(C / 32, F / 32), tb, 0, stream, W2, W2t, F, C);

    // LN1
    hipLaunchKernelGGL(ln_kernel, dim3(M), dim3(256), 0, stream, x, g1, b1, xn);

    // Fused QKV: [q|k] -> QK [M][1536], v -> vT [8][768][2048]
    hipLaunchKernelGGL((gemm_bt<4, 0>), dim3((3 * C) / BN, M / BM, 1), dim3(256), 0, stream,
                       xn, Wqt, (void*)QK, (void*)vT, nullptr, nullptr,
                       M, 3 * C, C, C, C, 0, 0LL, 0LL, 0LL, 1.0f);

    // S = scale * q @ k^T (causal tile pruning), bf16
    float scl = 1.0f / sqrtf((float)C);
    hipLaunchKernelGGL((gemm_bt<0, 1>), dim3(T / BN, T / BM, Bn), dim3(256), 0, stream,
                       QK, QK + 768, (void*)S, nullptr, nullptr, nullptr,
                       T, T, C, 1536, 1536, T,
                       (long long)T * 1536, (long long)T * 1536, (long long)T * T, scl);

    // causal softmax in place (live region only)
    hipLaunchKernelGGL(softmax_causal, dim3(M), dim3(256), 0, stream, S);

    // y = P @ V  (Bt = vT, K limited to m0+128)
    hipLaunchKernelGGL((gemm_bt<0, 2>), dim3(C / BN, T / BM, Bn), dim3(256), 0, stream,
                       S, vT, (void*)y, nullptr, nullptr, nullptr,
                       T, C, T, T, T, C,
                       (long long)T * T, (long long)C * T, (long long)T * C, 1.0f);

    // out = x + y@Wp + bp   (fp32)
    hipLaunchKernelGGL((gemm_bt<3, 0>), dim3(C / BN, M / BM, 1), dim3(256), 0, stream,
                       y, Wpt, (void*)out, nullptr, bp, x,
                       M, C, C, C, C, C, 0LL, 0LL, 0LL, 1.0f);

    // LN2
    hipLaunchKernelGGL(ln_kernel, dim3(M), dim3(256), 0, stream, out, g2, b2, xn);

    // h1 = gelu(xn2@W1 + bm1)  bf16
    hipLaunchKernelGGL((gemm_bt<2, 0>), dim3(F / BN, M / BM, 1), dim3(256), 0, stream,
                       xn, W1t, (void*)h1, nullptr, bm1, nullptr,
                       M, F, C, C, C, F, 0LL, 0LL, 0LL, 1.0f);

    // out = out + h1@W2 + bm2
    hipLaunchKernelGGL((gemm_bt<3, 0>), dim3(C / BN, M / BM, 1), dim3(256), 0, stream,
                       h1, W2t, (void*)out, nullptr, bm2, out,
                       M, C, F, F, F, C, 0LL, 0LL, 0LL, 1.0f);
}

// Round 4
// 608.126 us; speedup vs baseline: 1.5354x; 1.1441x over previous
//
#include <hip/hip_runtime.h>
#include <hip/hip_bf16.h>

// Transformer block: x:[8,2048,768] fp32. All GEMMs in bf16 MFMA (fp32 acc).
// GEMM: 128x128x64 tiles, 32x32x16 MFMA (2x2/wave), global_load_lds dwordx4,
// XOR bank swizzle, XCD-aware block swizzle, __launch_bounds__(256,4).
// Workspace layout (bytes):
//   [0          ) xn / xn2 bf16        25,165,824
//   [25165824   ) QK bf16 [16384][1536] 50,331,648   (aliased later by h1)
//   [75497472   ) vT bf16 [8][768][2048] 25,165,824  (h1)
//   [100663296  ) S/P bf16 [8][2048][2048] 67,108,864 (h1 head overlaps; dead by MLP)
//   [167772160  ) y bf16               25,165,824
//   [192937984  ) bf16 weights         14,155,776
// total: 207,093,760 bytes

typedef unsigned short u16;
typedef __bf16 bf16x8 __attribute__((ext_vector_type(8)));
typedef float  f32x4  __attribute__((ext_vector_type(4)));
typedef float  f32x16 __attribute__((ext_vector_type(16)));
typedef int    i32x4  __attribute__((ext_vector_type(4)));
typedef u16    u16x4  __attribute__((ext_vector_type(4)));
typedef u16    u16x8  __attribute__((ext_vector_type(8)));

__device__ __forceinline__ u16 f2b(float f) {
    __hip_bfloat16 h = __float2bfloat16(f);
    return *reinterpret_cast<u16*>(&h);
}
__device__ __forceinline__ float b2f(u16 u) {
    unsigned int x = ((unsigned int)u) << 16;
    return __uint_as_float(x);
}

// tanh-form gelu: gelu(x) = x * sigmoid(1.5957691*(x + 0.044715 x^3))
// folded into exp2: ~6 VALU ops. max err ~1e-3, far below bf16 noise.
__device__ __forceinline__ float fast_gelu(float v) {
    float t = v * v;
    float z = v * fmaf(0.10294294f, t, 2.30211842f);  // 2*0.79788456*log2(e)*(1, 0.044715)
    float e = exp2f(-z);                               // v_exp_f32
    return v * __builtin_amdgcn_rcpf(1.0f + e);
}

// async 16B global -> LDS. lds base must be wave-uniform; HW adds lane*16.
__device__ __forceinline__ void stage16(u16* lds_base_uniform, const u16* g, int lane) {
#if __has_builtin(__builtin_amdgcn_global_load_lds)
    __builtin_amdgcn_global_load_lds(
        (const __attribute__((address_space(1))) void*)g,
        (__attribute__((address_space(3))) void*)lds_base_uniform,
        16, 0, 0);
#else
    *(i32x4*)(lds_base_uniform + lane * 8) = *(const i32x4*)g;
#endif
}

// ---------------- transpose + cast fp32 -> bf16 -----------------
__global__ __launch_bounds__(256) void transpose_cast(const float* __restrict__ in,
                                                      u16* __restrict__ out,
                                                      int R, int Cc) {
    __shared__ float tile[32][33];
    int c0 = blockIdx.x * 32, r0 = blockIdx.y * 32;
    int tx = threadIdx.x, ty = threadIdx.y;
    for (int i = ty; i < 32; i += 8)
        tile[i][tx] = in[(long)(r0 + i) * Cc + c0 + tx];
    __syncthreads();
    for (int i = ty; i < 32; i += 8)
        out[(long)(c0 + i) * R + r0 + tx] = f2b(tile[tx][i]);
}

// ---------------- layernorm fp32 -> bf16 (float4 vectorized, 192 thr) -----------------
__global__ __launch_bounds__(192) void ln_kernel(const float* __restrict__ x,
                                                 const float* __restrict__ g,
                                                 const float* __restrict__ b,
                                                 u16* __restrict__ out) {
    const int C = 768;
    long row = blockIdx.x;
    const float* xr = x + row * C;
    int t = threadIdx.x;
    f32x4 v = *(const f32x4*)(xr + t * 4);
    float s = v[0] + v[1] + v[2] + v[3];
    float sq = v[0] * v[0] + v[1] * v[1] + v[2] * v[2] + v[3] * v[3];
#pragma unroll
    for (int o = 32; o; o >>= 1) {
        s += __shfl_xor(s, o);
        sq += __shfl_xor(sq, o);
    }
    __shared__ float ss[3], sq2[3];
    int wv = t >> 6;
    if ((t & 63) == 0) { ss[wv] = s; sq2[wv] = sq; }
    __syncthreads();
    s = ss[0] + ss[1] + ss[2];
    sq = sq2[0] + sq2[1] + sq2[2];
    float mu = s * (1.0f / 768.0f);
    float var = sq * (1.0f / 768.0f) - mu * mu;
    float rs = rsqrtf(var + 1e-5f);
    f32x4 gv = *(const f32x4*)(g + t * 4);
    f32x4 bv = *(const f32x4*)(b + t * 4);
    u16x4 pk;
#pragma unroll
    for (int j = 0; j < 4; j++) pk[j] = f2b((v[j] - mu) * rs * gv[j] + bv[j]);
    *(u16x4*)(out + row * C + t * 4) = pk;
}

// ---------------- causal softmax over bf16 scores, in place (u16x8 vectorized) --------
// Only the live region [0, ((t>>7)+1)<<7) is read/written; PV's K-limit reads exactly that.
__global__ __launch_bounds__(256) void softmax_causal(u16* __restrict__ S) {
    const int T = 2048;
    long row = blockIdx.x;
    int t = (int)(row & (T - 1));
    int ncols = ((t >> 7) + 1) << 7;
    u16* p = S + row * T;
    int tid = threadIdx.x;
    int base = tid * 8;
    bool act = base < ncols;
    float v[8];
    float mx = -3.0e38f;
    if (act) {
        u16x8 raw = *(const u16x8*)(p + base);
#pragma unroll
        for (int j = 0; j < 8; j++) {
            int col = base + j;
            v[j] = (col <= t) ? b2f(raw[j]) : -3.0e38f;
            mx = fmaxf(mx, v[j]);
        }
    }
#pragma unroll
    for (int o = 32; o; o >>= 1) mx = fmaxf(mx, __shfl_xor(mx, o));
    __shared__ float sm[4], ssum[4];
    int wv = tid >> 6;
    if ((tid & 63) == 0) sm[wv] = mx;
    __syncthreads();
    mx = fmaxf(fmaxf(sm[0], sm[1]), fmaxf(sm[2], sm[3]));
    float s = 0.0f;
    if (act) {
#pragma unroll
        for (int j = 0; j < 8; j++) {
            int col = base + j;
            float e = (col <= t) ? __expf(v[j] - mx) : 0.0f;
            v[j] = e;
            s += e;
        }
    }
#pragma unroll
    for (int o = 32; o; o >>= 1) s += __shfl_xor(s, o);
    if ((tid & 63) == 0) ssum[wv] = s;
    __syncthreads();
    s = ssum[0] + ssum[1] + ssum[2] + ssum[3];
    float inv = 1.0f / s;
    if (act) {
        u16x8 pk;
#pragma unroll
        for (int j = 0; j < 8; j++) pk[j] = f2b(v[j] * inv);
        *(u16x8*)(p + base) = pk;
    }
}

// ---------------- bf16 GEMM: C[M,N] = A[M,K] @ Bt[N,K]^T -------------
// 128x128 tile, BK=64, 4 waves 2x2, each wave 2x2 of 32x32x16 MFMA.
// LDS unpadded [128][64] (global_load_lds layout), XOR-swizzled 16B chunks.
// EPI: 0 bf16 store (scaled); 2 bf16 gelu(acc+bias); 3 f32 resid+acc+bias;
//      4 fused-QKV split (qk row-major ld 1536, v->vT)
// CAUSAL: 0 none; 1 skip tiles n0 >= m0+128; 2 K-loop limited to m0+128
#define BM 128
#define BN 128
#define BKT 64

template <int EPI, int CAUSAL>
__global__ __launch_bounds__(256, 4) void gemm_bt(const u16* __restrict__ A,
                                                  const u16* __restrict__ Bt,
                                                  void* __restrict__ Out,
                                                  void* __restrict__ Out2,
                                                  const float* __restrict__ bias,
                                                  const float* __restrict__ resid,
                                                  int M, int N, int K,
                                                  int lda, int ldb, int ldo,
                                                  long long sA, long long sB, long long sO,
                                                  float scale) {
    int bz = blockIdx.z;
    A += (long)bz * sA;
    Bt += (long)bz * sB;
    long obase = (long)bz * sO;

    // XCD-aware swizzle: contiguous x-major chunk per XCD (id%8 round-robin).
    int gx = gridDim.x;
    int nblk = gx * gridDim.y;
    int lin = blockIdx.y * gx + blockIdx.x;
    int chunk = nblk >> 3;
    int tile = (lin & 7) * chunk + (lin >> 3);
    int m0 = (tile / gx) * BM;
    int n0 = (tile % gx) * BN;

    if (CAUSAL == 1 && n0 >= m0 + BM) return;
    int kend = (CAUSAL == 2) ? ((K < m0 + BM) ? K : (m0 + BM)) : K;

    __shared__ __align__(16) u16 As[128 * 64];
    __shared__ __align__(16) u16 Bs[128 * 64];

    int tid = threadIdx.x;
    int lane = tid & 63;
    int l32 = lane & 31, kg = lane >> 5;   // fragment row, k-group
    int w = tid >> 6;
    int wm = (w >> 1) * 64, wn = (w & 1) * 64;

    f32x16 acc[2][2] = {};

    for (int k0 = 0; k0 < kend; k0 += BKT) {
#pragma unroll
        for (int i = 0; i < 4; i++) {
            int ebase = i * 256 + w * 64;         // wave-uniform chunk base
            int e = ebase + lane;
            int row = e >> 3;
            int gc = (e & 7) ^ (row & 7);         // XOR swizzle: fetch permuted chunk
            stage16(As + ebase * 8, A + (long)(m0 + row) * lda + k0 + gc * 8, lane);
            stage16(Bs + ebase * 8, Bt + (long)(n0 + row) * ldb + k0 + gc * 8, lane);
        }
        __syncthreads();
#pragma unroll
        for (int kk = 0; kk < 4; kk++) {          // K-step of 16
            int c = (kk << 1) + kg;               // chunk column 0..7
            bf16x8 af[2], bf[2];
#pragma unroll
            for (int mt = 0; mt < 2; mt++) {
                int r = wm + mt * 32 + l32;
                af[mt] = *(const bf16x8*)(As + r * 64 + ((c ^ (r & 7)) << 3));
            }
#pragma unroll
            for (int nt = 0; nt < 2; nt++) {
                int r = wn + nt * 32 + l32;
                bf[nt] = *(const bf16x8*)(Bs + r * 64 + ((c ^ (r & 7)) << 3));
            }
#pragma unroll
            for (int mt = 0; mt < 2; mt++)
#pragma unroll
                for (int nt = 0; nt < 2; nt++)
                    acc[mt][nt] = __builtin_amdgcn_mfma_f32_32x32x16_bf16(af[mt], bf[nt], acc[mt][nt], 0, 0, 0);
        }
        __syncthreads();
    }

    // C/D 32x32 layout: col = lane&31, row = (reg&3) + 8*(reg>>2) + 4*(lane>>5)
#pragma unroll
    for (int mt = 0; mt < 2; ++mt)
#pragma unroll
        for (int nt = 0; nt < 2; ++nt) {
            int col = n0 + wn + nt * 32 + l32;
            int rb = m0 + wm + mt * 32 + 4 * kg;
            f32x16 a = acc[mt][nt];
            if (EPI == 0) {
                u16* o = (u16*)Out + obase;
#pragma unroll
                for (int r = 0; r < 16; r++)
                    o[(long)(rb + (r & 3) + 8 * (r >> 2)) * ldo + col] = f2b(a[r] * scale);
            } else if (EPI == 2) {
                u16* o = (u16*)Out + obase;
                float bv = bias[col];
#pragma unroll
                for (int r = 0; r < 16; r++)
                    o[(long)(rb + (r & 3) + 8 * (r >> 2)) * ldo + col] = f2b(fast_gelu(a[r] + bv));
            } else if (EPI == 3) {
                float* o = (float*)Out + obase;
                float bv = bias[col];
#pragma unroll
                for (int r = 0; r < 16; r++) {
                    long idx = (long)(rb + (r & 3) + 8 * (r >> 2)) * ldo + col;
                    o[idx] = resid[idx] + a[r] + bv;
                }
            } else { // EPI 4: fused QKV. col<1536 -> qk [M][1536]; else v -> vT[b][c][t]
                if (col < 1536) {
                    u16* o = (u16*)Out;
#pragma unroll
                    for (int r = 0; r < 16; r++)
                        o[(long)(rb + (r & 3) + 8 * (r >> 2)) * 1536 + col] = f2b(a[r]);
                } else {
                    u16* o = (u16*)Out2;
                    int c = col - 1536;
#pragma unroll
                    for (int gi = 0; gi < 4; gi++) {
                        int row = rb + 8 * gi;          // rows row..row+3 consecutive
                        int b = row >> 11, t = row & 2047;
                        u16x4 pk;
#pragma unroll
                        for (int j = 0; j < 4; j++) pk[j] = f2b(a[gi * 4 + j]);
                        *(u16x4*)(o + ((long)b * 768 + c) * 2048 + t) = pk;
                    }
                }
            }
        }
}

extern "C" void kernel_launch(void* const* d_in, const int* in_sizes, int n_in,
                              void* d_out, int out_size, void* d_ws, size_t ws_size,
                              hipStream_t stream) {
    (void)in_sizes; (void)n_in; (void)out_size; (void)ws_size;
    const float* x   = (const float*)d_in[0];
    const float* Wq  = (const float*)d_in[1];
    const float* Wk  = (const float*)d_in[2];
    const float* Wv  = (const float*)d_in[3];
    const float* Wp  = (const float*)d_in[4];
    const float* bp  = (const float*)d_in[5];
    const float* g1  = (const float*)d_in[6];
    const float* b1  = (const float*)d_in[7];
    const float* g2  = (const float*)d_in[8];
    const float* b2  = (const float*)d_in[9];
    const float* W1  = (const float*)d_in[10];
    const float* bm1 = (const float*)d_in[11];
    const float* W2  = (const float*)d_in[12];
    const float* bm2 = (const float*)d_in[13];
    float* out = (float*)d_out;

    const int Bn = 8, T = 2048, C = 768, F = 3072;
    const int M = Bn * T; // 16384

    char* ws = (char*)d_ws;
    u16* xn = (u16*)(ws);
    u16* QK = (u16*)(ws + 25165824);   // [16384][1536]: q | k
    u16* vT = (u16*)(ws + 75497472);   // [8][768][2048]
    u16* S  = (u16*)(ws + 100663296);  // [8][2048][2048]
    u16* y  = (u16*)(ws + 167772160);
    u16* h1 = (u16*)(ws + 25165824);   // aliases QK/vT/S-head, all dead by MLP
    u16* wgt = (u16*)(ws + 192937984);
    u16* Wqt = wgt;                     // [2304][768] fused qkv^T (q|k|v rows)
    u16* Wkt = Wqt + 589824;
    u16* Wvt = Wkt + 589824;
    u16* Wpt = Wvt + 589824;
    u16* W1t = Wpt + 589824;            // [3072][768]
    u16* W2t = W1t + (long)C * F;       // [768][3072]

    dim3 tb(32, 8);
    hipLaunchKernelGGL(transpose_cast, dim3(C / 32, C / 32), tb, 0, stream, Wq, Wqt, C, C);
    hipLaunchKernelGGL(transpose_cast, dim3(C / 32, C / 32), tb, 0, stream, Wk, Wkt, C, C);
    hipLaunchKernelGGL(transpose_cast, dim3(C / 32, C / 32), tb, 0, stream, Wv, Wvt, C, C);
    hipLaunchKernelGGL(transpose_cast, dim3(C / 32, C / 32), tb, 0, stream, Wp, Wpt, C, C);
    hipLaunchKernelGGL(transpose_cast, dim3(F / 32, C / 32), tb, 0, stream, W1, W1t, C, F);
    hipLaunchKernelGGL(transpose_cast, dim3(C / 32, F / 32), tb, 0, stream, W2, W2t, F, C);

    // LN1
    hipLaunchKernelGGL(ln_kernel, dim3(M), dim3(192), 0, stream, x, g1, b1, xn);

    // Fused QKV: [q|k] -> QK [M][1536], v -> vT [8][768][2048]
    hipLaunchKernelGGL((gemm_bt<4, 0>), dim3((3 * C) / BN, M / BM, 1), dim3(256), 0, stream,
                       xn, Wqt, (void*)QK, (void*)vT, nullptr, nullptr,
                       M, 3 * C, C, C, C, 0, 0LL, 0LL, 0LL, 1.0f);

    // S = scale * q @ k^T (causal tile pruning), bf16
    float scl = 1.0f / sqrtf((float)C);
    hipLaunchKernelGGL((gemm_bt<0, 1>), dim3(T / BN, T / BM, Bn), dim3(256), 0, stream,
                       QK, QK + 768, (void*)S, nullptr, nullptr, nullptr,
                       T, T, C, 1536, 1536, T,
                       (long long)T * 1536, (long long)T * 1536, (long long)T * T, scl);

    // causal softmax in place (live region only)
    hipLaunchKernelGGL(softmax_causal, dim3(M), dim3(256), 0, stream, S);

    // y = P @ V  (Bt = vT, K limited to m0+128)
    hipLaunchKernelGGL((gemm_bt<0, 2>), dim3(C / BN, T / BM, Bn), dim3(256), 0, stream,
                       S, vT, (void*)y, nullptr, nullptr, nullptr,
                       T, C, T, T, T, C,
                       (long long)T * T, (long long)C * T, (long long)T * C, 1.0f);

    // out = x + y@Wp + bp   (fp32)
    hipLaunchKernelGGL((gemm_bt<3, 0>), dim3(C / BN, M / BM, 1), dim3(256), 0, stream,
                       y, Wpt, (void*)out, nullptr, bp, x,
                       M, C, C, C, C, C, 0LL, 0LL, 0LL, 1.0f);

    // LN2
    hipLaunchKernelGGL(ln_kernel, dim3(M), dim3(192), 0, stream, out, g2, b2, xn);

    // h1 = gelu(xn2@W1 + bm1)  bf16
    hipLaunchKernelGGL((gemm_bt<2, 0>), dim3(F / BN, M / BM, 1), dim3(256), 0, stream,
                       xn, W1t, (void*)h1, nullptr, bm1, nullptr,
                       M, F, C, C, C, F, 0LL, 0LL, 0LL, 1.0f);

    // out = out + h1@W2 + bm2
    hipLaunchKernelGGL((gemm_bt<3, 0>), dim3(C / BN, M / BM, 1), dim3(256), 0, stream,
                       h1, W2t, (void*)out, nullptr, bm2, out,
                       M, C, F, F, F, C, 0LL, 0LL, 0LL, 1.0f);
}